// Round 2
// baseline (699.786 us; speedup 1.0000x reference)
//
#include <hip/hip_runtime.h>
#include <hip/hip_bf16.h>

#define BATCH 4
#define NSEQ 4096
#define CDIM 256
#define CQKD 32
#define LOG2E 1.4426950408889634f

typedef float v4f __attribute__((ext_vector_type(4)));
typedef short v8s __attribute__((ext_vector_type(8)));

__device__ __forceinline__ float exp2_(float x) {
#if __has_builtin(__builtin_amdgcn_exp2f)
  return __builtin_amdgcn_exp2f(x);
#else
  return exp2f(x);
#endif
}

// manual RNE float->bf16 (bits) and back
__device__ __forceinline__ unsigned short f2bf(float x) {
  unsigned u = __builtin_bit_cast(unsigned, x);
  unsigned r = (u + 0x7FFFu + ((u >> 16) & 1u)) >> 16;
  return (unsigned short)r;
}
__device__ __forceinline__ float bf2f(unsigned short s) {
  unsigned u = ((unsigned)s) << 16;
  return __builtin_bit_cast(float, u);
}
// hot-path pack: 2 floats -> 2 bf16 in one dword
__device__ __forceinline__ unsigned int pack_bf16(float a, float b) {
#if __has_builtin(__builtin_amdgcn_cvt_pk_bf16_f32)
  typedef __bf16 v2bf __attribute__((ext_vector_type(2)));
  v2bf r = __builtin_amdgcn_cvt_pk_bf16_f32(a, b);
  return __builtin_bit_cast(unsigned int, r);
#else
  return ((unsigned)f2bf(b) << 16) | (unsigned)f2bf(a);
#endif
}

// ---------------- projection kernels ----------------
// out[b][n][o] = sum_ch W[o][ch]*in[b][ch][n] + bias[o]   (bf16, Q scaled by log2e)
__global__ __launch_bounds__(256) void proj_qk_kernel(
    const float* __restrict__ x, const float* __restrict__ y, const float* __restrict__ z,
    const float* __restrict__ q1w, const float* __restrict__ q1b,
    const float* __restrict__ k1w, const float* __restrict__ k1b,
    const float* __restrict__ k2w, const float* __restrict__ k2b,
    unsigned short* __restrict__ Q1, unsigned short* __restrict__ K1,
    unsigned short* __restrict__ K2) {
  const int which = blockIdx.z;
  const float* in = which == 0 ? x : (which == 1 ? y : z);
  const float* W  = which == 0 ? q1w : (which == 1 ? k1w : k2w);
  const float* bi = which == 0 ? q1b : (which == 1 ? k1b : k2b);
  unsigned short* out = which == 0 ? Q1 : (which == 1 ? K1 : K2);
  const float scale = which == 0 ? LOG2E : 1.0f;
  const int b = blockIdx.y;
  const int n = blockIdx.x * 64 + (threadIdx.x & 63);
  const int og = __builtin_amdgcn_readfirstlane(threadIdx.x >> 6);
  const float* inp = in + (size_t)(b * CDIM) * NSEQ + n;
  float acc[8];
#pragma unroll
  for (int j = 0; j < 8; ++j) acc[j] = 0.f;
  for (int ch = 0; ch < CDIM; ++ch) {
    float xv = inp[ch * NSEQ];
#pragma unroll
    for (int j = 0; j < 8; ++j) acc[j] += W[(og * 8 + j) * CDIM + ch] * xv;
  }
  union { unsigned short us[8]; uint4 u4; } pk;
#pragma unroll
  for (int j = 0; j < 8; ++j) pk.us[j] = f2bf((acc[j] + bi[og * 8 + j]) * scale);
  *(uint4*)(out + ((size_t)b * NSEQ + n) * CQKD + og * 8) = pk.u4;
}

// out[b][c][n] = sum_ch W[c][ch]*in[b][ch][n] + bias[c]   (bf16, keys contiguous)
__global__ __launch_bounds__(256) void proj_v_kernel(
    const float* __restrict__ y, const float* __restrict__ z,
    const float* __restrict__ v1w, const float* __restrict__ v1b,
    const float* __restrict__ v2w, const float* __restrict__ v2b,
    unsigned short* __restrict__ V1, unsigned short* __restrict__ V2) {
  const int which = blockIdx.z;
  const float* in = which == 0 ? y : z;
  const float* W  = which == 0 ? v1w : v2w;
  const float* bi = which == 0 ? v1b : v2b;
  unsigned short* out = which == 0 ? V1 : V2;
  const int b = blockIdx.y;
  const int n = blockIdx.x * 64 + (threadIdx.x & 63);
  const int cg = __builtin_amdgcn_readfirstlane(threadIdx.x >> 6);
  const float* inp = in + (size_t)(b * CDIM) * NSEQ + n;
  for (int pass = 0; pass < 4; ++pass) {
    const int cbase = pass * 64 + cg * 16;
    float acc[16];
#pragma unroll
    for (int i = 0; i < 16; ++i) acc[i] = 0.f;
    for (int ch = 0; ch < CDIM; ++ch) {
      float xv = inp[ch * NSEQ];
#pragma unroll
      for (int i = 0; i < 16; ++i) acc[i] += W[(cbase + i) * CDIM + ch] * xv;
    }
#pragma unroll
    for (int i = 0; i < 16; ++i)
      out[((size_t)b * CDIM + cbase + i) * NSEQ + n] = f2bf(acc[i] + bi[cbase + i]);
  }
}

__global__ __launch_bounds__(256) void wconv_kernel(const float* __restrict__ w,
                                                    unsigned short* __restrict__ o) {
  int i = blockIdx.x * 256 + threadIdx.x;
  if (i < CQKD * CDIM) o[i] = f2bf(w[i] * LOG2E);
}

// ---------------- fused double attention ----------------
// block = 256 threads = 4 waves: ks = wave>>1 (key half), ch = wave&1 (channel half)
// each wave: 32 queries (2 MFMA q-tiles) x 128 channels x 2048 keys, online softmax.
// S^T = mfma(A=Kfrag, B=Qfrag): lane holds scores of query lane&15 (keys quad*4+r).
// O^T = mfma(A=Vfrag, B=Pfrag): lane holds O[c=quad*4+r][q=lane&15] -> alpha/l align.
__device__ __forceinline__ void attn_loop(
    const unsigned short* __restrict__ Kp, const unsigned short* __restrict__ Vp,
    unsigned short* Pl, const v8s qf[2], int ks, int ch, int quad, int r15,
    v4f acc[2][8], float mcur[2], float lcur[2]) {
  const v4f vzero = {0.f, 0.f, 0.f, 0.f};
  const int key0 = ks * 2048;
  const unsigned short* vrow = Vp + (size_t)(ch * 128 + r15) * NSEQ + quad * 8;
  for (int kt = 0; kt < 32; ++kt) {
    const int kb0 = key0 + kt * 64;
    v8s kf[4];
#pragma unroll
    for (int kb = 0; kb < 4; ++kb)
      kf[kb] = *(const v8s*)(Kp + (kb0 + kb * 16 + r15) * CQKD + quad * 8);
#pragma unroll
    for (int qt = 0; qt < 2; ++qt) {
      v4f st[4];
#pragma unroll
      for (int kb = 0; kb < 4; ++kb)
        st[kb] = __builtin_amdgcn_mfma_f32_16x16x32_bf16(kf[kb], qf[qt], vzero, 0, 0, 0);
      float sv[16];
#pragma unroll
      for (int kb = 0; kb < 4; ++kb)
#pragma unroll
        for (int r = 0; r < 4; ++r) sv[kb * 4 + r] = st[kb][r];
      float mx = sv[0];
#pragma unroll
      for (int i = 1; i < 16; ++i) mx = fmaxf(mx, sv[i]);
      mx = fmaxf(mx, __shfl_xor(mx, 16));
      mx = fmaxf(mx, __shfl_xor(mx, 32));
      const float mnew = fmaxf(mcur[qt], mx);
      const float al = exp2_(mcur[qt] - mnew);
      mcur[qt] = mnew;
      float rs = 0.f;
#pragma unroll
      for (int i = 0; i < 16; ++i) { sv[i] = exp2_(sv[i] - mnew); rs += sv[i]; }
      rs += __shfl_xor(rs, 16);
      rs += __shfl_xor(rs, 32);
      lcur[qt] = lcur[qt] * al + rs;
      unsigned short* prow = Pl + (qt * 16 + r15) * 72 + quad * 4;
#pragma unroll
      for (int kb = 0; kb < 4; ++kb) {
        uint2 pk;
        pk.x = pack_bf16(sv[kb * 4 + 0], sv[kb * 4 + 1]);
        pk.y = pack_bf16(sv[kb * 4 + 2], sv[kb * 4 + 3]);
        *(uint2*)(prow + kb * 16) = pk;
      }
#pragma unroll
      for (int t = 0; t < 8; ++t) acc[qt][t] *= al;
    }
    v8s pf[2][2];
#pragma unroll
    for (int qt = 0; qt < 2; ++qt)
#pragma unroll
      for (int c = 0; c < 2; ++c)
        pf[qt][c] = *(const v8s*)(Pl + (qt * 16 + r15) * 72 + c * 32 + quad * 8);
#pragma unroll
    for (int t = 0; t < 8; ++t) {
      v8s vf0 = *(const v8s*)(vrow + (size_t)(t * 16) * NSEQ + kb0);
      v8s vf1 = *(const v8s*)(vrow + (size_t)(t * 16) * NSEQ + kb0 + 32);
      acc[0][t] = __builtin_amdgcn_mfma_f32_16x16x32_bf16(vf0, pf[0][0], acc[0][t], 0, 0, 0);
      acc[1][t] = __builtin_amdgcn_mfma_f32_16x16x32_bf16(vf0, pf[1][0], acc[1][t], 0, 0, 0);
      acc[0][t] = __builtin_amdgcn_mfma_f32_16x16x32_bf16(vf1, pf[0][1], acc[0][t], 0, 0, 0);
      acc[1][t] = __builtin_amdgcn_mfma_f32_16x16x32_bf16(vf1, pf[1][1], acc[1][t], 0, 0, 0);
    }
  }
}

// merge the two key-split partials; after this ks==0 waves hold full O, lf = denom
__device__ __forceinline__ void merge_partials(
    v4f acc[2][8], float mcur[2], float lcur[2], float* mergeO,
    float (*mbuf)[32], float (*lbuf)[32], int ks, int ch, int quad, int r15,
    float lf[2]) {
  if (ch == 0 && quad == 0) {
#pragma unroll
    for (int qt = 0; qt < 2; ++qt) {
      mbuf[ks][qt * 16 + r15] = mcur[qt];
      lbuf[ks][qt * 16 + r15] = lcur[qt];
    }
  }
  __syncthreads();
#pragma unroll
  for (int qt = 0; qt < 2; ++qt) {
    const int qi = qt * 16 + r15;
    const float m0 = mbuf[0][qi], m1 = mbuf[1][qi];
    const float mf = fmaxf(m0, m1);
    lf[qt] = lbuf[0][qi] * exp2_(m0 - mf) + lbuf[1][qi] * exp2_(m1 - mf);
    const float fs = exp2_(mcur[qt] - mf);
#pragma unroll
    for (int t = 0; t < 8; ++t) acc[qt][t] *= fs;
  }
  if (ks == 1) {
    float* mo = mergeO + ch * (128 * 33);
#pragma unroll
    for (int qt = 0; qt < 2; ++qt)
#pragma unroll
      for (int t = 0; t < 8; ++t)
#pragma unroll
        for (int r = 0; r < 4; ++r)
          mo[(t * 16 + quad * 4 + r) * 33 + qt * 16 + r15] = acc[qt][t][r];
  }
  __syncthreads();
  if (ks == 0) {
    const float* mo = mergeO + ch * (128 * 33);
#pragma unroll
    for (int qt = 0; qt < 2; ++qt)
#pragma unroll
      for (int t = 0; t < 8; ++t)
#pragma unroll
        for (int r = 0; r < 4; ++r)
          acc[qt][t][r] += mo[(t * 16 + quad * 4 + r) * 33 + qt * 16 + r15];
  }
}

__global__ __launch_bounds__(256, 2) void fused_attn_kernel(
    const unsigned short* __restrict__ Q1g, const unsigned short* __restrict__ K1g,
    const unsigned short* __restrict__ V1g, const unsigned short* __restrict__ K2g,
    const unsigned short* __restrict__ V2g, const unsigned short* __restrict__ W2g,
    const float* __restrict__ x, const float* __restrict__ q2b,
    const float* __restrict__ g1p, const float* __restrict__ g2p,
    float* __restrict__ outp) {
  __shared__ __align__(16) char uarea[33792];          // P buffers (18.4KB) / merge buffer (33KB), phase-disjoint
  __shared__ __align__(16) unsigned short out1s[CDIM * 33];  // out1 tile, bf16 [c][q]
  __shared__ __align__(16) unsigned short q2s[32 * 32];      // q2 tile, bf16 [q][o]
  __shared__ float mbuf[2][32];
  __shared__ float lbuf[2][32];

  const int tid = threadIdx.x;
  const int lane = tid & 63;
  const int w = tid >> 6;
  const int ks = w >> 1;
  const int ch = w & 1;
  const int quad = lane >> 4;
  const int r15 = lane & 15;
  const int b = blockIdx.x & 3;           // XCD-friendly: same batch stays on same XCDs
  const int n0 = (blockIdx.x >> 2) * 32;

  unsigned short* Pl = (unsigned short*)uarea + w * (32 * 72);
  float* mergeO = (float*)uarea;

  const float g1 = g1p[0];
  const float g2 = g2p[0];

  const unsigned short* Qp  = Q1g + (size_t)b * NSEQ * CQKD;
  const unsigned short* K1p = K1g + (size_t)b * NSEQ * CQKD;
  const unsigned short* K2p = K2g + (size_t)b * NSEQ * CQKD;
  const unsigned short* V1p = V1g + (size_t)b * CDIM * NSEQ;
  const unsigned short* V2p = V2g + (size_t)b * CDIM * NSEQ;

  v8s qf[2];
#pragma unroll
  for (int qt = 0; qt < 2; ++qt)
    qf[qt] = *(const v8s*)(Qp + (n0 + qt * 16 + r15) * CQKD + quad * 8);

  v4f acc[2][8];
  float mcur[2], lcur[2], lf[2];
  const v4f vzero = {0.f, 0.f, 0.f, 0.f};
#pragma unroll
  for (int qt = 0; qt < 2; ++qt) {
#pragma unroll
    for (int t = 0; t < 8; ++t) acc[qt][t] = vzero;
    mcur[qt] = -INFINITY;
    lcur[qt] = 0.f;
  }

  // ---- layer 1 ----
  attn_loop(K1p, V1p, Pl, qf, ks, ch, quad, r15, acc, mcur, lcur);
  merge_partials(acc, mcur, lcur, mergeO, mbuf, lbuf, ks, ch, quad, r15, lf);
  if (ks == 0) {
#pragma unroll
    for (int qt = 0; qt < 2; ++qt) {
      const float rinv = 1.0f / lf[qt];
#pragma unroll
      for (int t = 0; t < 8; ++t) {
        const int c = ch * 128 + t * 16 + quad * 4;
#pragma unroll
        for (int r = 0; r < 4; ++r) {
          float xres = x[((size_t)b * CDIM + c + r) * NSEQ + n0 + qt * 16 + r15];
          float v = g1 * (acc[qt][t][r] * rinv) + xres;
          out1s[(c + r) * 33 + qt * 16 + r15] = f2bf(v);
        }
      }
    }
  }
  __syncthreads();

  // ---- q2 projection from out1 (in LDS) ----
  {
    const int qi = tid & 31;
    const int og = tid >> 5;  // 0..7
    float a4[4] = {0.f, 0.f, 0.f, 0.f};
    for (int c = 0; c < CDIM; ++c) {
      float ov = bf2f(out1s[c * 33 + qi]);
#pragma unroll
      for (int i = 0; i < 4; ++i)
        a4[i] += bf2f(W2g[(og * 4 + i) * CDIM + c]) * ov;
    }
#pragma unroll
    for (int i = 0; i < 4; ++i)
      q2s[qi * 32 + og * 4 + i] = f2bf(a4[i] + q2b[og * 4 + i] * LOG2E);
  }
  __syncthreads();

  // ---- layer 2 ----
#pragma unroll
  for (int qt = 0; qt < 2; ++qt) {
    qf[qt] = *(const v8s*)(q2s + (qt * 16 + r15) * 32 + quad * 8);
#pragma unroll
    for (int t = 0; t < 8; ++t) acc[qt][t] = vzero;
    mcur[qt] = -INFINITY;
    lcur[qt] = 0.f;
  }
  attn_loop(K2p, V2p, Pl, qf, ks, ch, quad, r15, acc, mcur, lcur);
  merge_partials(acc, mcur, lcur, mergeO, mbuf, lbuf, ks, ch, quad, r15, lf);
  if (ks == 0) {
#pragma unroll
    for (int qt = 0; qt < 2; ++qt) {
      const float rinv = 1.0f / lf[qt];
#pragma unroll
      for (int t = 0; t < 8; ++t) {
        const int c = ch * 128 + t * 16 + quad * 4;
#pragma unroll
        for (int r = 0; r < 4; ++r) {
          float res = bf2f(out1s[(c + r) * 33 + qt * 16 + r15]);
          float v = g2 * (acc[qt][t][r] * rinv) + res;
          outp[((size_t)b * CDIM + c + r) * NSEQ + n0 + qt * 16 + r15] = v;
        }
      }
    }
  }
}

extern "C" void kernel_launch(void* const* d_in, const int* in_sizes, int n_in,
                              void* d_out, int out_size, void* d_ws, size_t ws_size,
                              hipStream_t stream) {
  const float* x   = (const float*)d_in[0];
  const float* y   = (const float*)d_in[1];
  const float* z   = (const float*)d_in[2];
  const float* q1w = (const float*)d_in[3];
  const float* q1b = (const float*)d_in[4];
  const float* k1w = (const float*)d_in[5];
  const float* k1b = (const float*)d_in[6];
  const float* v1w = (const float*)d_in[7];
  const float* v1b = (const float*)d_in[8];
  const float* g1  = (const float*)d_in[9];
  const float* q2w = (const float*)d_in[10];
  const float* q2b = (const float*)d_in[11];
  const float* k2w = (const float*)d_in[12];
  const float* k2b = (const float*)d_in[13];
  const float* v2w = (const float*)d_in[14];
  const float* v2b = (const float*)d_in[15];
  const float* g2  = (const float*)d_in[16];
  char* ws = (char*)d_ws;
  unsigned short* Q1 = (unsigned short*)(ws);
  unsigned short* K1 = (unsigned short*)(ws + (1u << 20));
  unsigned short* K2 = (unsigned short*)(ws + (2u << 20));
  unsigned short* V1 = (unsigned short*)(ws + (3u << 20));
  unsigned short* V2 = (unsigned short*)(ws + (11u << 20));
  unsigned short* W2 = (unsigned short*)(ws + (19u << 20));
  float* outp = (float*)d_out;

  proj_qk_kernel<<<dim3(64, 4, 3), 256, 0, stream>>>(x, y, z, q1w, q1b, k1w, k1b,
                                                     k2w, k2b, Q1, K1, K2);
  proj_v_kernel<<<dim3(64, 4, 2), 256, 0, stream>>>(y, z, v1w, v1b, v2w, v2b, V1, V2);
  wconv_kernel<<<dim3(32), 256, 0, stream>>>(q2w, W2);
  fused_attn_kernel<<<dim3(512), 256, 0, stream>>>(Q1, K1, V1, K2, V2, W2, x, q2b,
                                                   g1, g2, outp);
}

// Round 3
// 563.573 us; speedup vs baseline: 1.2417x; 1.2417x over previous
//
#include <hip/hip_runtime.h>
#include <hip/hip_bf16.h>

#define NSEQ 4096
#define CDIM 256
#define CQKD 32
#define LOG2E 1.4426950408889634f

typedef float v4f __attribute__((ext_vector_type(4)));
typedef short v8s __attribute__((ext_vector_type(8)));

__device__ __forceinline__ float exp2_(float x) {
#if __has_builtin(__builtin_amdgcn_exp2f)
  return __builtin_amdgcn_exp2f(x);
#else
  return exp2f(x);
#endif
}

__device__ __forceinline__ unsigned short f2bf(float x) {
  unsigned u = __builtin_bit_cast(unsigned, x);
  unsigned r = (u + 0x7FFFu + ((u >> 16) & 1u)) >> 16;
  return (unsigned short)r;
}
__device__ __forceinline__ float bf2f(unsigned short s) {
  unsigned u = ((unsigned)s) << 16;
  return __builtin_bit_cast(float, u);
}
__device__ __forceinline__ unsigned int pack_bf16(float a, float b) {
#if __has_builtin(__builtin_amdgcn_cvt_pk_bf16_f32)
  typedef __bf16 v2bf __attribute__((ext_vector_type(2)));
  v2bf r = __builtin_amdgcn_cvt_pk_bf16_f32(a, b);
  return __builtin_bit_cast(unsigned int, r);
#else
  return ((unsigned)f2bf(b) << 16) | (unsigned)f2bf(a);
#endif
}

// ---------------- weight convert (bf16; q2 pre-scaled by log2e) ----------------
// Wbf layout: [0,8192) q1 | [8192,16384) k1 | [16384,24576) k2 | [24576,32768) q2*log2e
//             | [32768,98304) v1 | [98304,163840) v2
__global__ __launch_bounds__(256) void convw_kernel(
    const float* __restrict__ q1w, const float* __restrict__ k1w,
    const float* __restrict__ k2w, const float* __restrict__ q2w,
    const float* __restrict__ v1w, const float* __restrict__ v2w,
    unsigned short* __restrict__ W) {
  int i = blockIdx.x * 256 + threadIdx.x;
  float v;
  if (i < 8192) v = q1w[i];
  else if (i < 16384) v = k1w[i - 8192];
  else if (i < 24576) v = k2w[i - 16384];
  else if (i < 32768) v = q2w[i - 24576] * LOG2E;
  else if (i < 98304) v = v1w[i - 32768];
  else v = v2w[i - 98304];
  W[i] = f2bf(v);
}

// ---------------- transpose+convert: [b][ch][n] fp32 -> [src][b][n][ch] bf16 ----------------
__global__ __launch_bounds__(256) void transpose_kernel(
    const float* __restrict__ x, const float* __restrict__ y,
    const float* __restrict__ z, unsigned short* __restrict__ inT) {
  __shared__ unsigned short t[64][73];
  const int src = blockIdx.z;
  const float* in = src == 0 ? x : (src == 1 ? y : z);
  const int b = blockIdx.y & 3, cht = blockIdx.y >> 2;
  const int n0 = blockIdx.x * 64, ch0 = cht * 64;
  const int tid = threadIdx.x;
  const float* ip = in + ((size_t)(b * CDIM + ch0)) * NSEQ + n0;
#pragma unroll
  for (int r = 0; r < 16; ++r) {
    int ch = r * 4 + (tid >> 6);
    int n = tid & 63;
    t[ch][n] = f2bf(ip[(size_t)ch * NSEQ + n]);
  }
  __syncthreads();
  unsigned short* op = inT + ((size_t)src * 4 + b) * NSEQ * CDIM + (size_t)n0 * CDIM + ch0;
#pragma unroll
  for (int r = 0; r < 8; ++r) {
    int n = r * 8 + (tid >> 5);
    int cp = tid & 31;
    unsigned int v = ((unsigned)t[cp * 2 + 1][n] << 16) | t[cp * 2][n];
    *(unsigned int*)(op + (size_t)n * CDIM + cp * 2) = v;
  }
}

// ---------------- MFMA projections ----------------
// D[m=seq][n=o] = inT-rows (A) x Wbf-rows (B); C/D: col(o)=lane&15, row(seq)=quad*4+reg
__global__ __launch_bounds__(256) void proj_qk_mfma(
    const unsigned short* __restrict__ inT, const unsigned short* __restrict__ Wbf,
    const float* __restrict__ q1b, const float* __restrict__ k1b,
    const float* __restrict__ k2b, unsigned short* __restrict__ Q1,
    unsigned short* __restrict__ K1, unsigned short* __restrict__ K2) {
  const int which = blockIdx.z;  // 0: x->Q1, 1: y->K1, 2: z->K2
  const unsigned short* Wp = Wbf + which * 8192;
  const float* bias = which == 0 ? q1b : (which == 1 ? k1b : k2b);
  unsigned short* out = which == 0 ? Q1 : (which == 1 ? K1 : K2);
  const float scale = which == 0 ? LOG2E : 1.0f;
  const int b = blockIdx.y;
  const int lane = threadIdx.x & 63, w = threadIdx.x >> 6;
  const int quad = lane >> 4, r15 = lane & 15;
  const int n0 = blockIdx.x * 64 + w * 16;
  const unsigned short* ip = inT + ((size_t)which * 4 + b) * NSEQ * CDIM;
  v4f acc[2];
  const v4f vzero = {0.f, 0.f, 0.f, 0.f};
  acc[0] = vzero; acc[1] = vzero;
#pragma unroll
  for (int cb = 0; cb < 8; ++cb) {
    v8s af = *(const v8s*)(ip + (size_t)(n0 + r15) * CDIM + cb * 32 + quad * 8);
    v8s b0 = *(const v8s*)(Wp + (0 * 16 + r15) * CDIM + cb * 32 + quad * 8);
    v8s b1 = *(const v8s*)(Wp + (1 * 16 + r15) * CDIM + cb * 32 + quad * 8);
    acc[0] = __builtin_amdgcn_mfma_f32_16x16x32_bf16(af, b0, acc[0], 0, 0, 0);
    acc[1] = __builtin_amdgcn_mfma_f32_16x16x32_bf16(af, b1, acc[1], 0, 0, 0);
  }
#pragma unroll
  for (int ot = 0; ot < 2; ++ot) {
    const float bv = bias[ot * 16 + r15];
#pragma unroll
    for (int r = 0; r < 4; ++r) {
      float v = (acc[ot][r] + bv) * scale;
      out[((size_t)b * NSEQ + n0 + quad * 4 + r) * CQKD + ot * 16 + r15] = f2bf(v);
    }
  }
}

__global__ __launch_bounds__(256) void proj_v_mfma(
    const unsigned short* __restrict__ inT, const unsigned short* __restrict__ Wbf,
    const float* __restrict__ v1b, const float* __restrict__ v2b,
    unsigned short* __restrict__ V1, unsigned short* __restrict__ V2) {
  const int which = blockIdx.z;  // 0: y->V1, 1: z->V2
  const unsigned short* Wp = Wbf + 32768 + which * 65536;
  const float* bias = which == 0 ? v1b : v2b;
  const int b = blockIdx.y;
  unsigned short* out = (which == 0 ? V1 : V2) + (size_t)b * CDIM * NSEQ;
  const unsigned short* ip = inT + ((size_t)(which + 1) * 4 + b) * NSEQ * CDIM;
  const int lane = threadIdx.x & 63, w = threadIdx.x >> 6;
  const int quad = lane >> 4, r15 = lane & 15;
  const int n0 = blockIdx.x * 64 + w * 16;
  v4f acc[16];
  const v4f vzero = {0.f, 0.f, 0.f, 0.f};
#pragma unroll
  for (int ot = 0; ot < 16; ++ot) acc[ot] = vzero;
#pragma unroll
  for (int cb = 0; cb < 8; ++cb) {
    v8s af = *(const v8s*)(ip + (size_t)(n0 + r15) * CDIM + cb * 32 + quad * 8);
#pragma unroll
    for (int ot = 0; ot < 16; ++ot) {
      v8s bf = *(const v8s*)(Wp + (ot * 16 + r15) * CDIM + cb * 32 + quad * 8);
      acc[ot] = __builtin_amdgcn_mfma_f32_16x16x32_bf16(af, bf, acc[ot], 0, 0, 0);
    }
  }
#pragma unroll
  for (int ot = 0; ot < 16; ++ot) {
    const int o = ot * 16 + r15;
    const float bv = bias[o];
    uint2 pk;
    pk.x = pack_bf16(acc[ot][0] + bv, acc[ot][1] + bv);
    pk.y = pack_bf16(acc[ot][2] + bv, acc[ot][3] + bv);
    *(uint2*)(out + (size_t)o * NSEQ + n0 + quad * 4) = pk;
  }
}

// ---------------- fused double attention ----------------
// block = 512 threads = 8 waves: ks = w>>1 (key quarter), ch = w&1 (channel half)
__device__ __forceinline__ void attn_loop(
    const unsigned short* __restrict__ Kp, const unsigned short* __restrict__ Vp,
    unsigned short* Pl, const v8s qf[2], int ks, int ch, int quad, int r15,
    v4f acc[2][8], float mcur[2], float lcur[2]) {
  const v4f vzero = {0.f, 0.f, 0.f, 0.f};
  const int key0 = ks * 1024;
  const unsigned short* vrow = Vp + (size_t)(ch * 128 + r15) * NSEQ + quad * 8;
  for (int kt = 0; kt < 16; ++kt) {
    const int kb0 = key0 + kt * 64;
    v8s kf[4];
#pragma unroll
    for (int kb = 0; kb < 4; ++kb)
      kf[kb] = *(const v8s*)(Kp + (kb0 + kb * 16 + r15) * CQKD + quad * 8);
#pragma unroll
    for (int qt = 0; qt < 2; ++qt) {
      v4f st[4];
#pragma unroll
      for (int kb = 0; kb < 4; ++kb)
        st[kb] = __builtin_amdgcn_mfma_f32_16x16x32_bf16(kf[kb], qf[qt], vzero, 0, 0, 0);
      float sv[16];
#pragma unroll
      for (int kb = 0; kb < 4; ++kb)
#pragma unroll
        for (int r = 0; r < 4; ++r) sv[kb * 4 + r] = st[kb][r];
      float mx = sv[0];
#pragma unroll
      for (int i = 1; i < 16; ++i) mx = fmaxf(mx, sv[i]);
      mx = fmaxf(mx, __shfl_xor(mx, 16));
      mx = fmaxf(mx, __shfl_xor(mx, 32));
      const float mnew = fmaxf(mcur[qt], mx);
      const float al = exp2_(mcur[qt] - mnew);
      mcur[qt] = mnew;
      float rs = 0.f;
#pragma unroll
      for (int i = 0; i < 16; ++i) { sv[i] = exp2_(sv[i] - mnew); rs += sv[i]; }
      rs += __shfl_xor(rs, 16);
      rs += __shfl_xor(rs, 32);
      lcur[qt] = lcur[qt] * al + rs;
      unsigned short* prow = Pl + (qt * 16 + r15) * 72 + quad * 4;
#pragma unroll
      for (int kb = 0; kb < 4; ++kb) {
        uint2 pk;
        pk.x = pack_bf16(sv[kb * 4 + 0], sv[kb * 4 + 1]);
        pk.y = pack_bf16(sv[kb * 4 + 2], sv[kb * 4 + 3]);
        *(uint2*)(prow + kb * 16) = pk;
      }
#pragma unroll
      for (int t = 0; t < 8; ++t) acc[qt][t] *= al;
    }
    v8s pf[2][2];
#pragma unroll
    for (int qt = 0; qt < 2; ++qt)
#pragma unroll
      for (int c = 0; c < 2; ++c)
        pf[qt][c] = *(const v8s*)(Pl + (qt * 16 + r15) * 72 + c * 32 + quad * 8);
#pragma unroll
    for (int t = 0; t < 8; ++t) {
      v8s vf0 = *(const v8s*)(vrow + (size_t)(t * 16) * NSEQ + kb0);
      v8s vf1 = *(const v8s*)(vrow + (size_t)(t * 16) * NSEQ + kb0 + 32);
      acc[0][t] = __builtin_amdgcn_mfma_f32_16x16x32_bf16(vf0, pf[0][0], acc[0][t], 0, 0, 0);
      acc[1][t] = __builtin_amdgcn_mfma_f32_16x16x32_bf16(vf0, pf[1][0], acc[1][t], 0, 0, 0);
      acc[0][t] = __builtin_amdgcn_mfma_f32_16x16x32_bf16(vf1, pf[0][1], acc[0][t], 0, 0, 0);
      acc[1][t] = __builtin_amdgcn_mfma_f32_16x16x32_bf16(vf1, pf[1][1], acc[1][t], 0, 0, 0);
    }
  }
}

// merge 4 key-split partials; ks==0 waves end with full O, lf = denominator
__device__ __forceinline__ void merge4(
    v4f acc[2][8], float mcur[2], float lcur[2], float* mergeO,
    float (*mbuf)[32], float (*lbuf)[32], int ks, int ch, int quad, int r15,
    float lf[2]) {
  if (ch == 0 && quad == 0) {
#pragma unroll
    for (int qt = 0; qt < 2; ++qt) {
      mbuf[ks][qt * 16 + r15] = mcur[qt];
      lbuf[ks][qt * 16 + r15] = lcur[qt];
    }
  }
  __syncthreads();
#pragma unroll
  for (int qt = 0; qt < 2; ++qt) {
    const int qi = qt * 16 + r15;
    float mf = fmaxf(fmaxf(mbuf[0][qi], mbuf[1][qi]), fmaxf(mbuf[2][qi], mbuf[3][qi]));
    lf[qt] = lbuf[0][qi] * exp2_(mbuf[0][qi] - mf) + lbuf[1][qi] * exp2_(mbuf[1][qi] - mf) +
             lbuf[2][qi] * exp2_(mbuf[2][qi] - mf) + lbuf[3][qi] * exp2_(mbuf[3][qi] - mf);
    const float fs = exp2_(mcur[qt] - mf);
#pragma unroll
    for (int t = 0; t < 8; ++t) acc[qt][t] *= fs;
  }
  for (int s = 1; s < 4; ++s) {
    if (ks == s) {
      float* mo = mergeO + ch * (128 * 33);
#pragma unroll
      for (int qt = 0; qt < 2; ++qt)
#pragma unroll
        for (int t = 0; t < 8; ++t)
#pragma unroll
          for (int r = 0; r < 4; ++r)
            mo[(t * 16 + quad * 4 + r) * 33 + qt * 16 + r15] = acc[qt][t][r];
    }
    __syncthreads();
    if (ks == 0) {
      const float* mo = mergeO + ch * (128 * 33);
#pragma unroll
      for (int qt = 0; qt < 2; ++qt)
#pragma unroll
        for (int t = 0; t < 8; ++t)
#pragma unroll
          for (int r = 0; r < 4; ++r)
            acc[qt][t][r] += mo[(t * 16 + quad * 4 + r) * 33 + qt * 16 + r15];
    }
    __syncthreads();
  }
}

__global__ __launch_bounds__(512, 4) void fused_attn_kernel(
    const unsigned short* __restrict__ Q1g, const unsigned short* __restrict__ K1g,
    const unsigned short* __restrict__ V1g, const unsigned short* __restrict__ K2g,
    const unsigned short* __restrict__ V2g, const unsigned short* __restrict__ W2g,
    const float* __restrict__ x, const float* __restrict__ q2b,
    const float* __restrict__ g1p, const float* __restrict__ g2p,
    float* __restrict__ outp) {
  __shared__ __align__(16) char uarea[36864];  // 8 P buffers (36.9KB) / merge buffer (33.8KB)
  __shared__ __align__(16) unsigned short out1s[CDIM * 33];
  __shared__ __align__(16) unsigned short q2s[32 * 32];
  __shared__ float mbuf[4][32];
  __shared__ float lbuf[4][32];

  const int tid = threadIdx.x;
  const int lane = tid & 63;
  const int w = tid >> 6;     // 0..7
  const int ks = w >> 1;      // key quarter 0..3
  const int ch = w & 1;       // channel half
  const int quad = lane >> 4;
  const int r15 = lane & 15;
  const int b = blockIdx.x & 3;
  const int n0 = (blockIdx.x >> 2) * 32;

  unsigned short* Pl = (unsigned short*)uarea + w * (32 * 72);
  float* mergeO = (float*)uarea;

  const float g1 = g1p[0];
  const float g2 = g2p[0];

  const unsigned short* Qp  = Q1g + (size_t)b * NSEQ * CQKD;
  const unsigned short* K1p = K1g + (size_t)b * NSEQ * CQKD;
  const unsigned short* K2p = K2g + (size_t)b * NSEQ * CQKD;
  const unsigned short* V1p = V1g + (size_t)b * CDIM * NSEQ;
  const unsigned short* V2p = V2g + (size_t)b * CDIM * NSEQ;

  v8s qf[2];
#pragma unroll
  for (int qt = 0; qt < 2; ++qt)
    qf[qt] = *(const v8s*)(Qp + (n0 + qt * 16 + r15) * CQKD + quad * 8);

  v4f acc[2][8];
  float mcur[2], lcur[2], lf[2];
  const v4f vzero = {0.f, 0.f, 0.f, 0.f};
#pragma unroll
  for (int qt = 0; qt < 2; ++qt) {
#pragma unroll
    for (int t = 0; t < 8; ++t) acc[qt][t] = vzero;
    mcur[qt] = -INFINITY;
    lcur[qt] = 0.f;
  }

  // ---- layer 1 ----
  attn_loop(K1p, V1p, Pl, qf, ks, ch, quad, r15, acc, mcur, lcur);
  merge4(acc, mcur, lcur, mergeO, mbuf, lbuf, ks, ch, quad, r15, lf);
  if (ks == 0) {
#pragma unroll
    for (int qt = 0; qt < 2; ++qt) {
      const float rinv = 1.0f / lf[qt];
#pragma unroll
      for (int t = 0; t < 8; ++t) {
        const int c = ch * 128 + t * 16 + quad * 4;
#pragma unroll
        for (int r = 0; r < 4; ++r) {
          float xres = x[((size_t)b * CDIM + c + r) * NSEQ + n0 + qt * 16 + r15];
          float v = g1 * (acc[qt][t][r] * rinv) + xres;
          out1s[(c + r) * 33 + qt * 16 + r15] = f2bf(v);
        }
      }
    }
  }
  __syncthreads();

  // ---- q2 projection from out1 (in LDS); W2g pre-scaled by log2e ----
  {
    const int qi = tid & 31;
    const int og = tid >> 5;  // 0..15, two outputs each
    float a2[2] = {0.f, 0.f};
    for (int c = 0; c < CDIM; ++c) {
      float ov = bf2f(out1s[c * 33 + qi]);
      a2[0] += bf2f(W2g[(og * 2 + 0) * CDIM + c]) * ov;
      a2[1] += bf2f(W2g[(og * 2 + 1) * CDIM + c]) * ov;
    }
#pragma unroll
    for (int i = 0; i < 2; ++i)
      q2s[qi * 32 + og * 2 + i] = f2bf(a2[i] + q2b[og * 2 + i] * LOG2E);
  }
  __syncthreads();

  // ---- layer 2 ----
#pragma unroll
  for (int qt = 0; qt < 2; ++qt) {
    qf[qt] = *(const v8s*)(q2s + (qt * 16 + r15) * 32 + quad * 8);
#pragma unroll
    for (int t = 0; t < 8; ++t) acc[qt][t] = vzero;
    mcur[qt] = -INFINITY;
    lcur[qt] = 0.f;
  }
  attn_loop(K2p, V2p, Pl, qf, ks, ch, quad, r15, acc, mcur, lcur);
  merge4(acc, mcur, lcur, mergeO, mbuf, lbuf, ks, ch, quad, r15, lf);
  if (ks == 0) {
#pragma unroll
    for (int qt = 0; qt < 2; ++qt) {
      const float rinv = 1.0f / lf[qt];
#pragma unroll
      for (int t = 0; t < 8; ++t) {
        const int c = ch * 128 + t * 16 + quad * 4;
#pragma unroll
        for (int r = 0; r < 4; ++r) {
          float res = bf2f(out1s[(c + r) * 33 + qt * 16 + r15]);
          float v = g2 * (acc[qt][t][r] * rinv) + res;
          outp[((size_t)b * CDIM + c + r) * NSEQ + n0 + qt * 16 + r15] = v;
        }
      }
    }
  }
}

extern "C" void kernel_launch(void* const* d_in, const int* in_sizes, int n_in,
                              void* d_out, int out_size, void* d_ws, size_t ws_size,
                              hipStream_t stream) {
  const float* x   = (const float*)d_in[0];
  const float* y   = (const float*)d_in[1];
  const float* z   = (const float*)d_in[2];
  const float* q1w = (const float*)d_in[3];
  const float* q1b = (const float*)d_in[4];
  const float* k1w = (const float*)d_in[5];
  const float* k1b = (const float*)d_in[6];
  const float* v1w = (const float*)d_in[7];
  const float* v1b = (const float*)d_in[8];
  const float* g1  = (const float*)d_in[9];
  const float* q2w = (const float*)d_in[10];
  const float* q2b = (const float*)d_in[11];
  const float* k2w = (const float*)d_in[12];
  const float* k2b = (const float*)d_in[13];
  const float* v2w = (const float*)d_in[14];
  const float* v2b = (const float*)d_in[15];
  const float* g2  = (const float*)d_in[16];
  char* ws = (char*)d_ws;
  // workspace layout (bytes)
  unsigned short* inT = (unsigned short*)(ws);                    // 25,165,824
  unsigned short* Wbf = (unsigned short*)(ws + 25165824);         // 327,680
  unsigned short* Q1  = (unsigned short*)(ws + 25493504);         // 1 MB
  unsigned short* K1  = (unsigned short*)(ws + 26542080);         // 1 MB
  unsigned short* K2  = (unsigned short*)(ws + 27590656);         // 1 MB
  unsigned short* V1  = (unsigned short*)(ws + 28639232);         // 8 MB
  unsigned short* V2  = (unsigned short*)(ws + 37027840);         // 8 MB -> 45,416,448 total
  float* outp = (float*)d_out;

  convw_kernel<<<dim3(640), 256, 0, stream>>>(q1w, k1w, k2w, q2w, v1w, v2w, Wbf);
  transpose_kernel<<<dim3(64, 16, 3), 256, 0, stream>>>(x, y, z, inT);
  proj_qk_mfma<<<dim3(64, 4, 3), 256, 0, stream>>>(inT, Wbf, q1b, k1b, k2b, Q1, K1, K2);
  proj_v_mfma<<<dim3(64, 4, 2), 256, 0, stream>>>(inT, Wbf, v1b, v2b, V1, V2);
  fused_attn_kernel<<<dim3(512), 512, 0, stream>>>(Q1, K1, V1, K2, V2, Wbf + 24576, x,
                                                   q2b, g1, g2, outp);
}